// Round 7
// baseline (131.725 us; speedup 1.0000x reference)
//
#include <hip/hip_runtime.h>
#include <math.h>

#define TPB 512

typedef float vf16 __attribute__((ext_vector_type(16)));
typedef float vf8  __attribute__((ext_vector_type(8)));
typedef float vf4  __attribute__((ext_vector_type(4)));

#define Z4 ((vf4){0.f, 0.f, 0.f, 0.f})

// One conv row segment (28 floats) via scalar loads. Early-clobber so the
// base pointer can never be allocated inside a destination tuple.
#define ISSUE3(A, B, C, P, O16, O8, O4)                     \
  asm volatile("s_load_dwordx16 %0, %3, " O16 "\n\t"        \
               "s_load_dwordx8  %1, %3, " O8 "\n\t"         \
               "s_load_dwordx4  %2, %3, " O4                \
               : "=&s"(A), "=&s"(B), "=&s"(C) : "s"(P))
// q==7: only 24 floats exist in-row; tail (C) is SAME-pad zeros.
#define ISSUE2F(A, B, P, O16, O8)                           \
  asm volatile("s_load_dwordx16 %0, %2, " O16 "\n\t"        \
               "s_load_dwordx8  %1, %2, " O8                \
               : "=&s"(A), "=&s"(B) : "s"(P))

// Wait for scalar loads; tying the tuples keeps their uses after the wait.
#define BIND6(A0, B0, C0, A1, B1, C1)                       \
  asm volatile("s_waitcnt lgkmcnt(0)"                       \
               : "+s"(A0), "+s"(B0), "+s"(C0),              \
                 "+s"(A1), "+s"(B1), "+s"(C1))
#define BIND4(A0, B0, A1, B1)                               \
  asm volatile("s_waitcnt lgkmcnt(0)"                       \
               : "+s"(A0), "+s"(B0), "+s"(A1), "+s"(B1))

// 36 FMAs for one kh-row: window floats 6v..6v+8 for v=0..3.
// A = floats 0..15, B = 16..23, C = 24..27 of the 28-float segment.
#define ROWFMA(A, B, C, K, U0, U1, U2, U3)                  \
  do {                                                      \
    U0 = fmaf(A[0],  w[K + 0], U0);                         \
    U0 = fmaf(A[1],  w[K + 1], U0);                         \
    U0 = fmaf(A[2],  w[K + 2], U0);                         \
    U0 = fmaf(A[3],  w[K + 3], U0);                         \
    U0 = fmaf(A[4],  w[K + 4], U0);                         \
    U0 = fmaf(A[5],  w[K + 5], U0);                         \
    U0 = fmaf(A[6],  w[K + 6], U0);                         \
    U0 = fmaf(A[7],  w[K + 7], U0);                         \
    U0 = fmaf(A[8],  w[K + 8], U0);                         \
    U1 = fmaf(A[6],  w[K + 0], U1);                         \
    U1 = fmaf(A[7],  w[K + 1], U1);                         \
    U1 = fmaf(A[8],  w[K + 2], U1);                         \
    U1 = fmaf(A[9],  w[K + 3], U1);                         \
    U1 = fmaf(A[10], w[K + 4], U1);                         \
    U1 = fmaf(A[11], w[K + 5], U1);                         \
    U1 = fmaf(A[12], w[K + 6], U1);                         \
    U1 = fmaf(A[13], w[K + 7], U1);                         \
    U1 = fmaf(A[14], w[K + 8], U1);                         \
    U2 = fmaf(A[12], w[K + 0], U2);                         \
    U2 = fmaf(A[13], w[K + 1], U2);                         \
    U2 = fmaf(A[14], w[K + 2], U2);                         \
    U2 = fmaf(A[15], w[K + 3], U2);                         \
    U2 = fmaf(B[0],  w[K + 4], U2);                         \
    U2 = fmaf(B[1],  w[K + 5], U2);                         \
    U2 = fmaf(B[2],  w[K + 6], U2);                         \
    U2 = fmaf(B[3],  w[K + 7], U2);                         \
    U2 = fmaf(B[4],  w[K + 8], U2);                         \
    U3 = fmaf(B[2],  w[K + 0], U3);                         \
    U3 = fmaf(B[3],  w[K + 1], U3);                         \
    U3 = fmaf(B[4],  w[K + 2], U3);                         \
    U3 = fmaf(B[5],  w[K + 3], U3);                         \
    U3 = fmaf(B[6],  w[K + 4], U3);                         \
    U3 = fmaf(B[7],  w[K + 5], U3);                         \
    U3 = fmaf(C[0],  w[K + 6], U3);                         \
    U3 = fmaf(C[1],  w[K + 7], U3);                         \
    U3 = fmaf(C[2],  w[K + 8], U3);                         \
  } while (0)

#define HEADOP(U0, U1, U2, U3, SM, S0, S1, S2, SP)          \
  do {                                                      \
    float f0 = fmaxf(U0, 0.f), f1 = fmaxf(U1, 0.f);         \
    float f2 = fmaxf(U2, 0.f), f3 = fmaxf(U3, 0.f);         \
    SM = fmaf(mw, (f0 + f1) + (f2 + f3), SM);               \
    S0 = fmaf(f0, qq0.x, S0); S1 = fmaf(f0, qq0.y, S1);     \
    S2 = fmaf(f0, qq0.z, S2); SP = fmaf(f0, qq0.w, SP);     \
    S0 = fmaf(f1, qq1.x, S0); S1 = fmaf(f1, qq1.y, S1);     \
    S2 = fmaf(f1, qq1.z, S2); SP = fmaf(f1, qq1.w, SP);     \
    S0 = fmaf(f2, qq2.x, S0); S1 = fmaf(f2, qq2.y, S1);     \
    S2 = fmaf(f2, qq2.z, S2); SP = fmaf(f2, qq2.w, SP);     \
    S0 = fmaf(f3, qq3.x, S0); S1 = fmaf(f3, qq3.y, S1);     \
    S2 = fmaf(f3, qq3.z, S2); SP = fmaf(f3, qq3.w, SP);     \
  } while (0)

// ---------------------------------------------------------------------------
// Prep: fused head table wq2[((hw>>2)*128 + c)*4 + (hw&3)] = {bw0,bw1,bw2,patc}
// patc = sum_{k: psi[k]==c} pat_w[hw*32+k]  (pat head is linear in feats).
// ---------------------------------------------------------------------------
__global__ __launch_bounds__(256)
void prep_weights(const float* __restrict__ base_w,  // [131072,3]
                  const float* __restrict__ pat_w,   // [32768]
                  const int*   __restrict__ psi,     // [32]
                  float4* __restrict__ wq2)          // [131072]
{
    int idx = blockIdx.x * 256 + threadIdx.x;        // 0..131071
    int hw = idx >> 7, c = idx & 127;
    const float* bp = base_w + (size_t)idx * 3;
    float b0 = bp[0], b1 = bp[1], b2 = bp[2];
    float pc = 0.f;
    const float* pr = pat_w + hw * 32;
    #pragma unroll
    for (int k = 0; k < 32; ++k)
        pc += (psi[k] == c) ? pr[k] : 0.f;
    wq2[(size_t)((hw >> 2) * 128 + c) * 4 + (hw & 3)] = make_float4(b0, b1, b2, pc);
}

// ---------------------------------------------------------------------------
// Main: grid 512 = qh(4) x sample-pair(128); 512 thr = 8 waves; lane=channel
// (c = tid&127), sg = wave-uniform spatial group. Conv window x is
// wave-uniform -> s_load into SGPRs (hot loop has ZERO LDS traffic); conv
// weights w[27] per-lane VGPRs, pinned in-loop; head weights via coalesced
// per-lane float4 quad from wq2 (L2-resident, one quad shared by both
// samples of the pair). Only one row-pair (56 SGPRs) in flight at a time.
// ---------------------------------------------------------------------------
__global__ __launch_bounds__(TPB, 4)
void pattern_branch_kernel(const float* __restrict__ in,      // [256,64,64,3]
                           const float* __restrict__ conv_w,  // [27,128]
                           const float* __restrict__ conv_b,  // [128]
                           const float* __restrict__ match_w, // [128]
                           const float4* __restrict__ wq2,    // [131072]
                           float* __restrict__ part)          // [4][10][128]
{
    __shared__ float red[8][10];

    const int bx  = blockIdx.x;            // 0..511
    const int qh  = bx >> 7;               // 0..3
    const int spr = bx & 127;              // samples 2spr, 2spr+1
    const int tid = threadIdx.x;
    const int c   = tid & 127;
    const int sg  = __builtin_amdgcn_readfirstlane(tid) >> 7;   // 0..3 uniform

    // conv weights: one channel per lane, VGPR-resident
    float w[27];
    #pragma unroll
    for (int k = 0; k < 27; ++k) w[k] = conv_w[k * 128 + c];
    float bias = conv_b[c];
    float mw   = match_w[c];

    const float* s0base = in + (size_t)(2 * spr) * 12288;
    const float4* wqp = wq2 + ((size_t)(64 * qh + 16 * sg) * 128 + c) * 4;

    float sm0 = 0.f, sa0 = 0.f, sb0 = 0.f, sc0 = 0.f, sp0 = 0.f;
    float sm1 = 0.f, sa1 = 0.f, sb1 = 0.f, sc1 = 0.f, sp1 = 0.f;

    #pragma unroll 1
    for (int m = 0; m < 16; ++m) {
        // pin conv weights every iteration: rematerialization is pointless
        #pragma unroll
        for (int k = 0; k < 27; ++k) asm volatile("" : "+v"(w[k]));
        asm volatile("" : "+v"(bias), "+v"(mw));

        const int oh = 8 * qh + 2 * sg + (m >> 3);
        const int q  = m & 7;
        const float* r0 = s0base + 2 * oh * 192 + 24 * q;  // uniform ptr
        const bool qt   = (q < 7);
        const bool r2ok = (oh < 31);                       // SAME row pad

        // head quads (vector path, vmcnt — overlaps the scalar-fed FMAs)
        float4 qq0 = wqp[0], qq1 = wqp[1], qq2 = wqp[2], qq3 = wqp[3];
        wqp += 512;                                        // next slot

        float u0 = bias, u1 = bias, u2 = bias, u3 = bias;  // sample 0
        float t0 = bias, t1 = bias, t2 = bias, t3 = bias;  // sample 1

        vf16 A0, A1; vf8 B0, B1; vf4 C0, C1;

        // ---- kh = 0 (row 2*oh), both samples
        if (qt) {
            ISSUE3(A0, B0, C0, r0, "0", "64", "96");
            ISSUE3(A1, B1, C1, r0, "49152", "49216", "49248");
            BIND6(A0, B0, C0, A1, B1, C1);
        } else {
            ISSUE2F(A0, B0, r0, "0", "64");
            ISSUE2F(A1, B1, r0, "49152", "49216");
            C0 = Z4; C1 = Z4;
            BIND4(A0, B0, A1, B1);
        }
        ROWFMA(A0, B0, C0, 0, u0, u1, u2, u3);
        ROWFMA(A1, B1, C1, 0, t0, t1, t2, t3);

        // ---- kh = 1 (row 2*oh+1, +768 B)
        if (qt) {
            ISSUE3(A0, B0, C0, r0, "768", "832", "864");
            ISSUE3(A1, B1, C1, r0, "49920", "49984", "50016");
            BIND6(A0, B0, C0, A1, B1, C1);
        } else {
            ISSUE2F(A0, B0, r0, "768", "832");
            ISSUE2F(A1, B1, r0, "49920", "49984");
            C0 = Z4; C1 = Z4;
            BIND4(A0, B0, A1, B1);
        }
        ROWFMA(A0, B0, C0, 9, u0, u1, u2, u3);
        ROWFMA(A1, B1, C1, 9, t0, t1, t2, t3);

        // ---- kh = 2 (row 2*oh+2, +1536 B) — skipped at oh==31 (zeros)
        if (r2ok) {
            if (qt) {
                ISSUE3(A0, B0, C0, r0, "1536", "1600", "1632");
                ISSUE3(A1, B1, C1, r0, "50688", "50752", "50784");
                BIND6(A0, B0, C0, A1, B1, C1);
            } else {
                ISSUE2F(A0, B0, r0, "1536", "1600");
                ISSUE2F(A1, B1, r0, "50688", "50752");
                C0 = Z4; C1 = Z4;
                BIND4(A0, B0, A1, B1);
            }
            ROWFMA(A0, B0, C0, 18, u0, u1, u2, u3);
            ROWFMA(A1, B1, C1, 18, t0, t1, t2, t3);
        }

        HEADOP(u0, u1, u2, u3, sm0, sa0, sb0, sc0, sp0);
        HEADOP(t0, t1, t2, t3, sm1, sa1, sb1, sc1, sp1);
    }

    // ---- reduction: lanes are channels -> shuffle, then LDS across 8 waves
    float vals[10] = { sm0, sa0, sb0, sc0, sp0, sm1, sa1, sb1, sc1, sp1 };
    #pragma unroll
    for (int off = 32; off > 0; off >>= 1)
        #pragma unroll
        for (int v = 0; v < 10; ++v)
            vals[v] += __shfl_down(vals[v], off, 64);
    int wv = tid >> 6;
    if ((tid & 63) == 0) {
        #pragma unroll
        for (int v = 0; v < 10; ++v) red[wv][v] = vals[v];
    }
    __syncthreads();
    if (tid < 10) {
        float t = 0.f;
        #pragma unroll
        for (int wj = 0; wj < 8; ++wj) t += red[wj][tid];
        part[(qh * 10 + tid) * 128 + spr] = t;
    }
}

// ---------------------------------------------------------------------------
// Finalize: thread b sums its 4 quarter-partials and routes.
// ---------------------------------------------------------------------------
__global__ __launch_bounds__(256)
void finalize_kernel(const float* __restrict__ part,    // [4][10][128]
                     const float* __restrict__ match_b,
                     const float* __restrict__ pat_b,
                     const float* __restrict__ base_b,
                     float* __restrict__ out)           // [256,3]
{
    int b   = threadIdx.x;
    int s01 = b & 1, spr = b >> 1;
    float t[5] = { 0.f, 0.f, 0.f, 0.f, 0.f };
    #pragma unroll
    for (int j = 0; j < 4; ++j)
        #pragma unroll
        for (int v = 0; v < 5; ++v)
            t[v] += part[(j * 10 + s01 * 5 + v) * 128 + spr];
    float score = t[0] * (1.f / 1024.f) + match_b[0];
    float p = 1.f / (1.f + expf(-(t[4] + pat_b[0])));
    float l0 = t[1] + base_b[0], l1 = t[2] + base_b[1], l2 = t[3] + base_b[2];
    float m = fmaxf(l0, fmaxf(l1, l2));
    float e0 = expf(l0 - m), e1 = expf(l1 - m), e2 = expf(l2 - m);
    float inv = 1.f / (e0 + e1 + e2);
    bool use_pat = (score > 0.f) && (p >= 0.5f);
    float o0, o1, o2;
    if (use_pat) { o0 = p; o1 = 0.5f * (1.f - p); o2 = o1; }
    else         { o0 = e0 * inv; o1 = e1 * inv; o2 = e2 * inv; }
    out[b * 3 + 0] = o0;
    out[b * 3 + 1] = o1;
    out[b * 3 + 2] = o2;
}

extern "C" void kernel_launch(void* const* d_in, const int* in_sizes, int n_in,
                              void* d_out, int out_size, void* d_ws, size_t ws_size,
                              hipStream_t stream) {
    const float* in      = (const float*)d_in[0];
    const float* conv_w  = (const float*)d_in[1];
    const float* conv_b  = (const float*)d_in[2];
    const float* match_w = (const float*)d_in[3];
    const float* match_b = (const float*)d_in[4];
    const float* pat_w   = (const float*)d_in[5];
    const float* pat_b   = (const float*)d_in[6];
    const float* base_w  = (const float*)d_in[7];
    const float* base_b  = (const float*)d_in[8];
    const int*   psi     = (const int*)d_in[9];
    float* out = (float*)d_out;

    float4* wq2  = (float4*)d_ws;                                // 2 MB
    float*  part = (float*)((char*)d_ws + (size_t)131072 * 16);  // 20 KB

    prep_weights<<<512, 256, 0, stream>>>(base_w, pat_w, psi, wq2);

    pattern_branch_kernel<<<512, TPB, 0, stream>>>(
        in, conv_w, conv_b, match_w, wq2, part);

    finalize_kernel<<<1, 256, 0, stream>>>(part, match_b, pat_b, base_b, out);
}